// Round 17
// baseline (56.934 us; speedup 1.0000x reference)
//
#include <hip/hip_runtime.h>
#include <hip/hip_bf16.h>

// Sizes (static per reference)
#define HGT 56
#define WID 56
#define SPA 3136          // 56*56
#define CCH 256
#define C3  768
#define NH  8
#define HD  32
#define YB  2408448       // 768*3136 per-batch elem count
#define ISTR 43008        // 56*768  (reshaped NCHW-flat view: per-i stride)
#define JSTR 768          // per-j stride
#define SCALE_Q 0.17677669529663687f   // 32^-0.5

typedef __attribute__((ext_vector_type(8))) short short8;
typedef __attribute__((ext_vector_type(4))) float f32x4;

static __device__ __forceinline__ unsigned short f2bf_bits(float f) {
    __hip_bfloat16 h = __float2bfloat16(f);
    union { __hip_bfloat16 h; unsigned short u; } cv; cv.h = h; return cv.u;
}
static __device__ __forceinline__ float bfu(unsigned short u) {
    union { unsigned x; float f; } c; c.x = (unsigned)u << 16; return c.f;
}
static __device__ __forceinline__ unsigned pk2bf(float a, float b) {
    return ((unsigned)f2bf_bits(b) << 16) | (unsigned)f2bf_bits(a);
}

// ---------------- cvt: xT (z<2) + weights (z==2) in one dispatch (r11 verbatim)
__global__ __launch_bounds__(256) void k_cvt(const float* __restrict__ x,
                                             const float* __restrict__ w1,
                                             const float* __restrict__ wp,
                                             __hip_bfloat16* __restrict__ xT,
                                             __hip_bfloat16* __restrict__ w1b,
                                             __hip_bfloat16* __restrict__ wpb) {
    __shared__ __align__(16) __hip_bfloat16 Sl[64][80];   // 160B rows
    const int t = threadIdx.x;
    const int z = blockIdx.z;
    if (z == 2) {   // weights: w1 (196608) then wp (65536), grid-stride x4
        const int gid = (blockIdx.y * 49 + blockIdx.x) * 256 + t;
        for (int i = gid * 4; i < 262144; i += 200704) {
            const float* src;
            __hip_bfloat16* dst;
            if (i < 196608) { src = w1 + i; dst = w1b + i; }
            else            { src = wp + (i - 196608); dst = wpb + (i - 196608); }
            float4 v = *(const float4*)src;
            ushort4 u;
            u.x = f2bf_bits(v.x); u.y = f2bf_bits(v.y);
            u.z = f2bf_bits(v.z); u.w = f2bf_bits(v.w);
            *(ushort4*)dst = u;
        }
        return;
    }
    const int b = z, c0 = blockIdx.y * 64, s0 = blockIdx.x * 64;
    const float* xb = x + (size_t)b * (CCH * SPA);
    const int sq = (t & 15) * 4, cq = (t >> 4) * 4;   // 4x4 micro-tile
    float4 r[4];
#pragma unroll
    for (int rr = 0; rr < 4; ++rr)
        r[rr] = *(const float4*)&xb[(size_t)(c0 + cq + rr) * SPA + s0 + sq];
#pragma unroll
    for (int j = 0; j < 4; ++j) {
        ushort4 u;
        u.x = f2bf_bits(((const float*)&r[0])[j]);
        u.y = f2bf_bits(((const float*)&r[1])[j]);
        u.z = f2bf_bits(((const float*)&r[2])[j]);
        u.w = f2bf_bits(((const float*)&r[3])[j]);
        *(ushort4*)&Sl[sq + j][cq] = u;
    }
    __syncthreads();
    const int srow = t >> 2, cslot = t & 3;
    __hip_bfloat16* dst = &xT[(size_t)b * SPA * CCH + (size_t)(s0 + srow) * CCH + c0];
    short8 v0 = *(const short8*)&Sl[srow][cslot * 8];
    short8 v1 = *(const short8*)&Sl[srow][(cslot + 4) * 8];
    *(short8*)&dst[cslot * 8] = v0;
    *(short8*)&dst[(cslot + 4) * 8] = v1;
}

// ---------------- K1: qkv GEMM, 128(o) x 64(s) tile, BK=64 (r15 body)
// + XCD-aware bijective block swizzle (588 = 8*73 + 4); B-tile-sharing blocks
// are XCD-contiguous (bx = wg/12).
__global__ __launch_bounds__(256) void k_qkv2(const __hip_bfloat16* __restrict__ A,
                                              const __hip_bfloat16* __restrict__ B,
                                              __hip_bfloat16* __restrict__ C) {
    __shared__ __align__(16) short sA[8192];   // 128 rows x 128B, swizzled
    __shared__ __align__(16) short sB[4096];   // 64 rows x 128B, swizzled
    const int t = threadIdx.x;
    const int lane = t & 63, wv = t >> 6;
    // XCD swizzle
    const int lid = blockIdx.z * 294 + blockIdx.y * 49 + blockIdx.x;
    const int xcd = lid & 7, kk_ = lid >> 3;
    const int wg = (xcd < 4) ? xcd * 74 + kk_ : 296 + (xcd - 4) * 73 + kk_;
    const int bx = wg / 12, rr_ = wg - bx * 12;
    const int by = rr_ >> 1, bz = rr_ & 1;
    const int s0 = bx * 64, o0 = by * 128, b = bz;
    const __hip_bfloat16* Bb = B + (size_t)b * SPA * CCH;

    const int srow = t >> 3;                   // 0..31
    const int scol = (t & 7) ^ (srow & 7);     // (row+32r)&7 == row&7
    const char* gA = (const char*)(A  + (size_t)(o0 + srow) * CCH) + scol * 16;
    const char* gB = (const char*)(Bb + (size_t)(s0 + srow) * CCH) + scol * 16;
    char* lA = (char*)sA + wv * 1024;
    char* lB = (char*)sB + wv * 1024;

    const int lr = lane & 15, kh = lane >> 4;

    f32x4 acc[2][4] = {};
    for (int kt = 0; kt < 4; ++kt) {
#pragma unroll
        for (int r = 0; r < 4; ++r)            // A rows 32r + srow
            __builtin_amdgcn_global_load_lds(
                (const __attribute__((address_space(1))) void*)(gA + r * 16384 + kt * 128),
                (__attribute__((address_space(3))) void*)(lA + r * 4096), 16, 0, 0);
        __builtin_amdgcn_global_load_lds(
            (const __attribute__((address_space(1))) void*)(gB + kt * 128),
            (__attribute__((address_space(3))) void*)lB, 16, 0, 0);
        __builtin_amdgcn_global_load_lds(
            (const __attribute__((address_space(1))) void*)(gB + 16384 + kt * 128),
            (__attribute__((address_space(3))) void*)(lB + 4096), 16, 0, 0);
        __syncthreads();
#pragma unroll
        for (int kk = 0; kk < 2; ++kk) {
            const int g = (kk << 2) | kh;
            short8 af[2], bf[4];
#pragma unroll
            for (int mi = 0; mi < 2; ++mi) {
                const int ar = wv * 32 + mi * 16 + lr;
                af[mi] = *(const short8*)((char*)sA + ar * 128 + ((g ^ (ar & 7)) << 4));
            }
#pragma unroll
            for (int ni = 0; ni < 4; ++ni) {
                const int br = ni * 16 + lr;
                bf[ni] = *(const short8*)((char*)sB + br * 128 + ((g ^ (br & 7)) << 4));
            }
#pragma unroll
            for (int mi = 0; mi < 2; ++mi)
#pragma unroll
                for (int ni = 0; ni < 4; ++ni)
                    acc[mi][ni] = __builtin_amdgcn_mfma_f32_16x16x32_bf16(
                        af[mi], bf[ni], acc[mi][ni], 0, 0, 0);
        }
        __syncthreads();
    }
    __hip_bfloat16* Cb = C + (size_t)b * C3 * SPA;
#pragma unroll
    for (int mi = 0; mi < 2; ++mi)
#pragma unroll
        for (int ni = 0; ni < 4; ++ni) {
            const int r0 = o0 + wv * 32 + mi * 16 + kh * 4;
            const int cc = s0 + ni * 16 + lr;
#pragma unroll
            for (int q = 0; q < 4; ++q)
                Cb[(size_t)(r0 + q) * SPA + cc] = __float2bfloat16(acc[mi][ni][q]);
        }
}

// ---------------- proj GEMM (r11 body) + XCD swizzle (392 = 8*49 exact);
// B-tile-sharing blocks XCD-contiguous (bx = wg/8).
template<bool OBF>
__global__ __launch_bounds__(256) void k_gemm(const __hip_bfloat16* __restrict__ A,
                                              const __hip_bfloat16* __restrict__ B,
                                              void* __restrict__ Cv, int M) {
    __shared__ __align__(16) short sA[4096];   // 64 rows x 128B, swizzled
    __shared__ __align__(16) short sB[4096];
    const int t = threadIdx.x;
    const int lane = t & 63, w = t >> 6;
    // XCD swizzle (grid fixed at (49,4,2) = 392)
    const int lid = blockIdx.z * 196 + blockIdx.y * 49 + blockIdx.x;
    const int wg = (lid & 7) * 49 + (lid >> 3);
    const int bx = wg >> 3, rr_ = wg & 7;
    const int s0 = bx * 64, o0 = (rr_ >> 1) * 64, b = rr_ & 1;
    const __hip_bfloat16* Bb = B + (size_t)b * SPA * CCH;

    const int srow = t >> 3;
    const int scol = (t & 7) ^ (srow & 7);
    const char* gA = (const char*)(A  + (size_t)(o0 + srow) * CCH) + scol * 16;
    const char* gB = (const char*)(Bb + (size_t)(s0 + srow) * CCH) + scol * 16;
    char* lA = (char*)sA + w * 1024;
    char* lB = (char*)sB + w * 1024;

    const int wm = w >> 1, wn = w & 1;
    const int lr = lane & 15, kh = lane >> 4;
    const int ar0 = wm * 32 + lr, ar1 = ar0 + 16;
    const int br0 = wn * 32 + lr, br1 = br0 + 16;

    f32x4 acc[2][2] = {};
    for (int kt = 0; kt < 4; ++kt) {
        __builtin_amdgcn_global_load_lds(
            (const __attribute__((address_space(1))) void*)(gA + kt * 128),
            (__attribute__((address_space(3))) void*)lA, 16, 0, 0);
        __builtin_amdgcn_global_load_lds(
            (const __attribute__((address_space(1))) void*)(gA + 16384 + kt * 128),
            (__attribute__((address_space(3))) void*)(lA + 4096), 16, 0, 0);
        __builtin_amdgcn_global_load_lds(
            (const __attribute__((address_space(1))) void*)(gB + kt * 128),
            (__attribute__((address_space(3))) void*)lB, 16, 0, 0);
        __builtin_amdgcn_global_load_lds(
            (const __attribute__((address_space(1))) void*)(gB + 16384 + kt * 128),
            (__attribute__((address_space(3))) void*)(lB + 4096), 16, 0, 0);
        __syncthreads();
#pragma unroll
        for (int kk = 0; kk < 2; ++kk) {
            const int kg = (kk << 2) | kh;
            short8 a0 = *(const short8*)&sA[(ar0 * 128 + ((kg ^ (ar0 & 7)) << 4)) >> 1];
            short8 a1 = *(const short8*)&sA[(ar1 * 128 + ((kg ^ (ar1 & 7)) << 4)) >> 1];
            short8 b0 = *(const short8*)&sB[(br0 * 128 + ((kg ^ (br0 & 7)) << 4)) >> 1];
            short8 b1 = *(const short8*)&sB[(br1 * 128 + ((kg ^ (br1 & 7)) << 4)) >> 1];
            acc[0][0] = __builtin_amdgcn_mfma_f32_16x16x32_bf16(a0, b0, acc[0][0], 0, 0, 0);
            acc[0][1] = __builtin_amdgcn_mfma_f32_16x16x32_bf16(a0, b1, acc[0][1], 0, 0, 0);
            acc[1][0] = __builtin_amdgcn_mfma_f32_16x16x32_bf16(a1, b0, acc[1][0], 0, 0, 0);
            acc[1][1] = __builtin_amdgcn_mfma_f32_16x16x32_bf16(a1, b1, acc[1][1], 0, 0, 0);
        }
        __syncthreads();
    }
#pragma unroll
    for (int mi = 0; mi < 2; ++mi)
#pragma unroll
        for (int ni = 0; ni < 2; ++ni) {
            const int r0 = o0 + wm * 32 + mi * 16 + kh * 4;
            const int cc = s0 + wn * 32 + ni * 16 + lr;
            if constexpr (OBF) {
                __hip_bfloat16* Cb = (__hip_bfloat16*)Cv + (size_t)b * M * SPA;
#pragma unroll
                for (int q = 0; q < 4; ++q)
                    Cb[(size_t)(r0 + q) * SPA + cc] = __float2bfloat16(acc[mi][ni][q]);
            } else {
                float* Cb = (float*)Cv + (size_t)b * M * SPA;
#pragma unroll
                for (int q = 0; q < 4; ++q)
                    Cb[(size_t)(r0 + q) * SPA + cc] = acc[mi][ni][q];
            }
        }
}

// ---------------- K2: depthwise 3x3 SAME, x4 along w, bf16 in/out (r11 verbatim)
__global__ __launch_bounds__(256) void k_dw(const __hip_bfloat16* __restrict__ y1,
                                            const float* __restrict__ w2,
                                            __hip_bfloat16* __restrict__ y2) {
    int idx = blockIdx.x * 256 + threadIdx.x;   // 1204224 exact
    int tw = idx % 14;
    int rest = idx / 14;
    int h = rest % HGT;
    int bc = rest / HGT;
    int w0 = tw * 4;
    const __hip_bfloat16* in = y1 + (size_t)bc * SPA;
    const float* wt = w2 + (bc % C3) * 9;
    float a0 = 0.f, a1 = 0.f, a2 = 0.f, a3 = 0.f;
#pragma unroll
    for (int dh = -1; dh <= 1; ++dh) {
        int hh = h + dh;
        if (hh < 0 || hh >= HGT) continue;
        const __hip_bfloat16* rp = in + hh * WID + w0;
        ushort4 c4 = *(const ushort4*)rp;
        float c0 = bfu(c4.x), c1 = bfu(c4.y), c2 = bfu(c4.z), c3 = bfu(c4.w);
        float l = (w0 > 0)  ? bfu(*(const unsigned short*)(rp - 1)) : 0.f;
        float r = (w0 < 52) ? bfu(*(const unsigned short*)(rp + 4)) : 0.f;
        float wl = wt[(dh + 1) * 3 + 0];
        float wc = wt[(dh + 1) * 3 + 1];
        float wr = wt[(dh + 1) * 3 + 2];
        a0 += wl * l  + wc * c0 + wr * c1;
        a1 += wl * c0 + wc * c1 + wr * c2;
        a2 += wl * c1 + wc * c2 + wr * c3;
        a3 += wl * c2 + wc * c3 + wr * r;
    }
    ushort4 o;
    o.x = f2bf_bits(a0); o.y = f2bf_bits(a1);
    o.z = f2bf_bits(a2); o.w = f2bf_bits(a3);
    *(ushort4*)(y2 + (size_t)bc * SPA + h * WID + w0) = o;
}

// ---------------- K3 v7e: MFMA attention (r16 body verbatim)
template<int D>
__device__ __forceinline__ void attn7_body(short* __restrict__ sK,
                                           short* __restrict__ sVT,
                                           short* __restrict__ sQ,
                                           short* __restrict__ sP,
                                           float* __restrict__ sEB,
                                           const __hip_bfloat16* __restrict__ y2,
                                           const float* __restrict__ rpb,
                                           __hip_bfloat16* __restrict__ opre,
                                           int b, int head, int i, int hsub) {
    const int tid = threadIdx.x;
    const int lane = tid & 63, w = tid >> 6;
    const int lr = lane & 15, kh = lane >> 4;

    int wsi, pbi;
    if (D == 1) {
        wsi = (i < 3) ? 0 : ((i > 52) ? 49 : i - 3);
        pbi = (i < 3) ? 6 - i : ((i > 52) ? 55 - i : 3);
    } else {
        wsi = (i < 6) ? (i & 1) : ((i >= 50) ? 42 + (i & 1) : i - 6);
        pbi = (i < 6) ? 6 - (i >> 1) : ((i >= 50) ? (55 - i) >> 1 : 3);
    }

    const __hip_bfloat16* base  = y2 + (size_t)b * YB + head * HD;
    const __hip_bfloat16* kbase = base + CCH     + wsi * ISTR;
    const __hip_bfloat16* vbase = base + 2 * CCH + wsi * ISTR;
    const __hip_bfloat16* qbase = base + i * ISTR;

    // ---- K stage: [u 7][kj 64][d 32], rows 64B, XOR key kj&3; kj>=56 clamped
    for (int f = tid; f < 1792; f += 256) {
        int u = f >> 8, rem = f & 255, kj = rem >> 2, slot = rem & 3;
        int kjc = (kj > 55) ? 55 : kj;
        const __hip_bfloat16* src = kbase + u * (D * ISTR) + kjc * JSTR + ((slot ^ (kj & 3)) << 3);
        char* dst = (char*)sK + (size_t)(f - lane) * 16;
        __builtin_amdgcn_global_load_lds(
            (const __attribute__((address_space(1))) void*)src,
            (__attribute__((address_space(3))) void*)dst, 16, 0, 0);
    }
    // ---- Q stage: [j 64][d 32]; rows >=56 clamped (unused)
    {
        int jq = tid >> 2, slot = tid & 3;
        int jqc = (jq > 55) ? 55 : jq;
        const __hip_bfloat16* src = qbase + jqc * JSTR + ((slot ^ (jq & 3)) << 3);
        char* dst = (char*)sQ + (size_t)(tid - lane) * 16;
        __builtin_amdgcn_global_load_lds(
            (const __attribute__((address_space(1))) void*)src,
            (__attribute__((address_space(3))) void*)dst, 16, 0, 0);
    }
    // ---- V^T stage (16B-wide): [u 7][d 32][kj 64], rows 128B, XOR key d&7.
    for (int f = tid; f < 784; f += 256) {
        int u = f / 112, rem = f - u * 112;
        int dq8 = rem / 28, kjp = rem - dq8 * 28;
        const __hip_bfloat16* g0 = vbase + u * (D * ISTR) + (2 * kjp) * JSTR + dq8 * 8;
        short8 va8 = *(const short8*)g0;
        short8 vb8 = *(const short8*)(g0 + JSTR);
        const int kjhi = kjp >> 2;
        char* bvt = (char*)sVT + (u * 32 + dq8 * 8) * 128 + (kjp & 3) * 4;
#pragma unroll
        for (int e = 0; e < 8; ++e) {
            unsigned pk = (unsigned)(unsigned short)va8[e] |
                          ((unsigned)(unsigned short)vb8[e] << 16);
            *(unsigned*)(bvt + e * 128 + ((kjhi ^ e) << 4)) = pk;
        }
    }
    if (tid < 224) {   // V^T pad (kj 56..63) = 0
        int u = tid >> 5, d = tid & 31;
        int row = u * 32 + d;
        int byt = row * 128 + ((7 ^ (d & 7)) << 4);
        *(short8*)((char*)sVT + byt) = (short8){0, 0, 0, 0, 0, 0, 0, 0};
    }
    if (tid < 91) {
        int u = tid / 13, r = tid - u * 13;
        sEB[tid] = __expf(rpb[hsub * 169 + (pbi + u) * 13 + r]);
    }
    __syncthreads();

    const int j = w * 16 + lr;
    int wsj;
    if (D == 1) wsj = (j < 3) ? 0 : ((j > 52) ? 49 : j - 3);
    else        wsj = (j < 6) ? (j & 1) : ((j >= 50) ? 42 + (j & 1) : j - 6);

    short8 qf = *(const short8*)((char*)sQ + j * 64 + ((kh ^ (j & 3)) << 4));

    // ---- hoisted u-invariant mask + bias-row index
    int rr[16];
    unsigned vmask = 0;
#pragma unroll
    for (int Mt = 0; Mt < 4; ++Mt)
#pragma unroll
        for (int q = 0; q < 4; ++q) {
            const int idx = Mt * 4 + q;
            const int kj = Mt * 16 + (kh << 2) + q;
            const int rel = kj - j;
            const int din = kj - wsj;
            bool valid = (din >= 0) && (din <= 6 * D);
            if (D == 2) valid = valid && ((rel & 1) == 0);
            const int r = (D == 1) ? (rel + 6) : ((rel >> 1) + 6);
            rr[idx] = valid ? r : 0;           // valid r is in [0,12]; 0 is safe
            vmask |= (valid ? 1u : 0u) << idx;
        }

    float ssum = 0.f;
    f32x4 oacc0 = {0.f, 0.f, 0.f, 0.f};
    f32x4 oacc1 = {0.f, 0.f, 0.f, 0.f};
    short* sPw = sP + w * 2048;

#pragma unroll
    for (int u = 0; u < 7; ++u) {
        char* sPb = (char*)(sPw + (u & 1) * 1024);
        f32x4 s[4];
#pragma unroll
        for (int Mt = 0; Mt < 4; ++Mt) {
            int kjrow = u * 64 + Mt * 16 + lr;
            short8 kf = *(const short8*)((char*)sK + kjrow * 64 + ((kh ^ (lr & 3)) << 4));
            s[Mt] = __builtin_amdgcn_mfma_f32_16x16x32_bf16(kf, qf,
                        (f32x4){0.f, 0.f, 0.f, 0.f}, 0, 0, 0);
        }
        const float* ebu = sEB + u * 13;
#pragma unroll
        for (int Mt = 0; Mt < 4; ++Mt) {
            float ev[4];
#pragma unroll
            for (int q = 0; q < 4; ++q) {
                const int idx = Mt * 4 + q;
                float ex = __expf(s[Mt][q] * SCALE_Q) * ebu[rr[idx]];
                ev[q] = ((vmask >> idx) & 1u) ? ex : 0.f;
                ssum += ev[q];
            }
            uint2 pk2;
            pk2.x = pk2bf(ev[0], ev[1]);
            pk2.y = pk2bf(ev[2], ev[3]);
            int g = Mt * 2 + (kh >> 1);
            int byt = lr * 128 + (((g ^ (lr & 7)) << 4)) + (kh & 1) * 8;
            *(uint2*)(sPb + byt) = pk2;
        }
        // ---- fence: order P-pack writes before PV fragment reads
        __syncthreads();
#pragma unroll
        for (int Kt = 0; Kt < 2; ++Kt) {
            short8 pf = *(const short8*)(sPb + lr * 128 + ((((Kt * 4 + kh) ^ (lr & 7)) << 4)));
            {
                int row = u * 32 + lr;
                short8 vf = *(const short8*)((char*)sVT + row * 128 +
                              ((((Kt * 4 + kh) ^ (lr & 7)) << 4)));
                oacc0 = __builtin_amdgcn_mfma_f32_16x16x32_bf16(vf, pf, oacc0, 0, 0, 0);
            }
            {
                int row = u * 32 + 16 + lr;
                short8 vf = *(const short8*)((char*)sVT + row * 128 +
                              ((((Kt * 4 + kh) ^ (lr & 7)) << 4)));
                oacc1 = __builtin_amdgcn_mfma_f32_16x16x32_bf16(vf, pf, oacc1, 0, 0, 0);
            }
        }
    }

    // full softmax denominator: combine the 4 kh-group partials (same j = lr)
    ssum += __shfl_xor(ssum, 16);
    ssum += __shfl_xor(ssum, 32);

    if (j < 56) {
        const float rinv = __frcp_rn(ssum);
        const size_t ob = (size_t)b * (SPA * CCH) + (size_t)(i * WID + j) * CCH
                          + head * HD + (kh << 2);
        uint2 p0, p1;
        p0.x = pk2bf(oacc0[0] * rinv, oacc0[1] * rinv);
        p0.y = pk2bf(oacc0[2] * rinv, oacc0[3] * rinv);
        p1.x = pk2bf(oacc1[0] * rinv, oacc1[1] * rinv);
        p1.y = pk2bf(oacc1[2] * rinv, oacc1[3] * rinv);
        *(uint2*)&opre[ob]      = p0;
        *(uint2*)&opre[ob + 16] = p1;
    }
}

__global__ __launch_bounds__(256) void k_attn7(const __hip_bfloat16* __restrict__ y2,
                                               const float* __restrict__ rpb0,
                                               const float* __restrict__ rpb1,
                                               __hip_bfloat16* __restrict__ opre) {
    __shared__ __align__(16) short sK[14336];    // 28KB
    __shared__ __align__(16) short sVT[14336];   // 28KB
    __shared__ __align__(16) short sQ[2048];     // 4KB
    __shared__ __align__(16) short sP[8192];     // 16KB (4 waves x 2 bufs)
    __shared__ float sEB[91];
    // XCD swizzle: 896 = 8 * 112; each XCD gets 2 full (b,head) groups
    const int lid = blockIdx.y * 56 + blockIdx.x;
    const int wg = (lid & 7) * 112 + (lid >> 3);
    const int bh = wg / 56, i = wg - bh * 56;
    const int b = bh >> 3, head = bh & 7;
    if (head < 4)
        attn7_body<1>(sK, sVT, sQ, sP, sEB, y2, rpb0, opre, b, head, i, head);
    else
        attn7_body<2>(sK, sVT, sQ, sP, sEB, y2, rpb1, opre, b, head, i, head - 4);
}

extern "C" void kernel_launch(void* const* d_in, const int* in_sizes, int n_in,
                              void* d_out, int out_size, void* d_ws, size_t ws_size,
                              hipStream_t stream) {
    const float* x    = (const float*)d_in[0];
    const float* w1   = (const float*)d_in[1];
    const float* w2   = (const float*)d_in[2];
    const float* rpb0 = (const float*)d_in[3];
    const float* rpb1 = (const float*)d_in[4];
    const float* wp   = (const float*)d_in[5];
    float* out = (float*)d_out;

    float* p = (float*)d_ws;
    __hip_bfloat16* y1b  = (__hip_bfloat16*)p;             // [2][768][3136] bf16
    __hip_bfloat16* y2b  = (__hip_bfloat16*)(p + YB);      // [2][768][3136] bf16
    __hip_bfloat16* xT   = (__hip_bfloat16*)(p + 2 * YB);  // [2][3136][256] bf16
    __hip_bfloat16* opre = xT;                             // disjoint lifetimes
    __hip_bfloat16* w1b  = (__hip_bfloat16*)(p + 2 * YB + 802816);
    __hip_bfloat16* wpb  = (__hip_bfloat16*)(p + 2 * YB + 802816 + 98304);

    k_cvt<<<dim3(49, 4, 3), 256, 0, stream>>>(x, w1, wp, xT, w1b, wpb);
    k_qkv2<<<dim3(49, 6, 2), 256, 0, stream>>>(w1b, xT, y1b);
    k_dw<<<dim3(4704), 256, 0, stream>>>(y1b, w2, y2b);
    k_attn7<<<dim3(HGT, 2 * NH), 256, 0, stream>>>(y2b, rpb0, rpb1, opre);
    k_gemm<false><<<dim3(49, 4, 2), 256, 0, stream>>>(wpb, opre, out, CCH);
}

// Round 18
// 55.963 us; speedup vs baseline: 1.0173x; 1.0173x over previous
//
#include <hip/hip_runtime.h>
#include <hip/hip_bf16.h>

// Sizes (static per reference)
#define HGT 56
#define WID 56
#define SPA 3136          // 56*56
#define CCH 256
#define C3  768
#define NH  8
#define HD  32
#define YB  2408448       // 768*3136 per-batch elem count
#define ISTR 43008        // 56*768  (reshaped NCHW-flat view: per-i stride)
#define JSTR 768          // per-j stride
#define SCALE_Q 0.17677669529663687f   // 32^-0.5

typedef __attribute__((ext_vector_type(8))) short short8;
typedef __attribute__((ext_vector_type(4))) float f32x4;

static __device__ __forceinline__ unsigned short f2bf_bits(float f) {
    __hip_bfloat16 h = __float2bfloat16(f);
    union { __hip_bfloat16 h; unsigned short u; } cv; cv.h = h; return cv.u;
}
static __device__ __forceinline__ float bfu(unsigned short u) {
    union { unsigned x; float f; } c; c.x = (unsigned)u << 16; return c.f;
}
static __device__ __forceinline__ unsigned pk2bf(float a, float b) {
    return ((unsigned)f2bf_bits(b) << 16) | (unsigned)f2bf_bits(a);
}

// ---------------- cvt: xT (z<2) + weights (z==2) in one dispatch (r11 verbatim)
__global__ __launch_bounds__(256) void k_cvt(const float* __restrict__ x,
                                             const float* __restrict__ w1,
                                             const float* __restrict__ wp,
                                             __hip_bfloat16* __restrict__ xT,
                                             __hip_bfloat16* __restrict__ w1b,
                                             __hip_bfloat16* __restrict__ wpb) {
    __shared__ __align__(16) __hip_bfloat16 Sl[64][80];   // 160B rows
    const int t = threadIdx.x;
    const int z = blockIdx.z;
    if (z == 2) {   // weights: w1 (196608) then wp (65536), grid-stride x4
        const int gid = (blockIdx.y * 49 + blockIdx.x) * 256 + t;
        for (int i = gid * 4; i < 262144; i += 200704) {
            const float* src;
            __hip_bfloat16* dst;
            if (i < 196608) { src = w1 + i; dst = w1b + i; }
            else            { src = wp + (i - 196608); dst = wpb + (i - 196608); }
            float4 v = *(const float4*)src;
            ushort4 u;
            u.x = f2bf_bits(v.x); u.y = f2bf_bits(v.y);
            u.z = f2bf_bits(v.z); u.w = f2bf_bits(v.w);
            *(ushort4*)dst = u;
        }
        return;
    }
    const int b = z, c0 = blockIdx.y * 64, s0 = blockIdx.x * 64;
    const float* xb = x + (size_t)b * (CCH * SPA);
    const int sq = (t & 15) * 4, cq = (t >> 4) * 4;   // 4x4 micro-tile
    float4 r[4];
#pragma unroll
    for (int rr = 0; rr < 4; ++rr)
        r[rr] = *(const float4*)&xb[(size_t)(c0 + cq + rr) * SPA + s0 + sq];
#pragma unroll
    for (int j = 0; j < 4; ++j) {
        ushort4 u;
        u.x = f2bf_bits(((const float*)&r[0])[j]);
        u.y = f2bf_bits(((const float*)&r[1])[j]);
        u.z = f2bf_bits(((const float*)&r[2])[j]);
        u.w = f2bf_bits(((const float*)&r[3])[j]);
        *(ushort4*)&Sl[sq + j][cq] = u;
    }
    __syncthreads();
    const int srow = t >> 2, cslot = t & 3;
    __hip_bfloat16* dst = &xT[(size_t)b * SPA * CCH + (size_t)(s0 + srow) * CCH + c0];
    short8 v0 = *(const short8*)&Sl[srow][cslot * 8];
    short8 v1 = *(const short8*)&Sl[srow][(cslot + 4) * 8];
    *(short8*)&dst[cslot * 8] = v0;
    *(short8*)&dst[(cslot + 4) * 8] = v1;
}

// ---------------- K1: qkv GEMM, 128(o) x 64(s) tile, BK=64 (r15/r16 verbatim)
__global__ __launch_bounds__(256) void k_qkv2(const __hip_bfloat16* __restrict__ A,
                                              const __hip_bfloat16* __restrict__ B,
                                              __hip_bfloat16* __restrict__ C) {
    __shared__ __align__(16) short sA[8192];   // 128 rows x 128B, swizzled
    __shared__ __align__(16) short sB[4096];   // 64 rows x 128B, swizzled
    const int t = threadIdx.x;
    const int lane = t & 63, wv = t >> 6;
    const int s0 = blockIdx.x * 64, o0 = blockIdx.y * 128, b = blockIdx.z;
    const __hip_bfloat16* Bb = B + (size_t)b * SPA * CCH;

    const int srow = t >> 3;                   // 0..31
    const int scol = (t & 7) ^ (srow & 7);     // (row+32r)&7 == row&7
    const char* gA = (const char*)(A  + (size_t)(o0 + srow) * CCH) + scol * 16;
    const char* gB = (const char*)(Bb + (size_t)(s0 + srow) * CCH) + scol * 16;
    char* lA = (char*)sA + wv * 1024;
    char* lB = (char*)sB + wv * 1024;

    const int lr = lane & 15, kh = lane >> 4;

    f32x4 acc[2][4] = {};
    for (int kt = 0; kt < 4; ++kt) {
#pragma unroll
        for (int r = 0; r < 4; ++r)            // A rows 32r + srow
            __builtin_amdgcn_global_load_lds(
                (const __attribute__((address_space(1))) void*)(gA + r * 16384 + kt * 128),
                (__attribute__((address_space(3))) void*)(lA + r * 4096), 16, 0, 0);
        __builtin_amdgcn_global_load_lds(
            (const __attribute__((address_space(1))) void*)(gB + kt * 128),
            (__attribute__((address_space(3))) void*)lB, 16, 0, 0);
        __builtin_amdgcn_global_load_lds(
            (const __attribute__((address_space(1))) void*)(gB + 16384 + kt * 128),
            (__attribute__((address_space(3))) void*)(lB + 4096), 16, 0, 0);
        __syncthreads();
#pragma unroll
        for (int kk = 0; kk < 2; ++kk) {
            const int g = (kk << 2) | kh;
            short8 af[2], bf[4];
#pragma unroll
            for (int mi = 0; mi < 2; ++mi) {
                const int ar = wv * 32 + mi * 16 + lr;
                af[mi] = *(const short8*)((char*)sA + ar * 128 + ((g ^ (ar & 7)) << 4));
            }
#pragma unroll
            for (int ni = 0; ni < 4; ++ni) {
                const int br = ni * 16 + lr;
                bf[ni] = *(const short8*)((char*)sB + br * 128 + ((g ^ (br & 7)) << 4));
            }
#pragma unroll
            for (int mi = 0; mi < 2; ++mi)
#pragma unroll
                for (int ni = 0; ni < 4; ++ni)
                    acc[mi][ni] = __builtin_amdgcn_mfma_f32_16x16x32_bf16(
                        af[mi], bf[ni], acc[mi][ni], 0, 0, 0);
        }
        __syncthreads();
    }
    __hip_bfloat16* Cb = C + (size_t)b * C3 * SPA;
#pragma unroll
    for (int mi = 0; mi < 2; ++mi)
#pragma unroll
        for (int ni = 0; ni < 4; ++ni) {
            const int r0 = o0 + wv * 32 + mi * 16 + kh * 4;
            const int cc = s0 + ni * 16 + lr;
#pragma unroll
            for (int q = 0; q < 4; ++q)
                Cb[(size_t)(r0 + q) * SPA + cc] = __float2bfloat16(acc[mi][ni][q]);
        }
}

// ---------------- bf16 MFMA GEMM (r11 verbatim; used for proj, OBF=false)
template<bool OBF>
__global__ __launch_bounds__(256) void k_gemm(const __hip_bfloat16* __restrict__ A,
                                              const __hip_bfloat16* __restrict__ B,
                                              void* __restrict__ Cv, int M) {
    __shared__ __align__(16) short sA[4096];   // 64 rows x 128B, swizzled
    __shared__ __align__(16) short sB[4096];
    const int t = threadIdx.x;
    const int lane = t & 63, w = t >> 6;
    const int s0 = blockIdx.x * 64, o0 = blockIdx.y * 64, b = blockIdx.z;
    const __hip_bfloat16* Bb = B + (size_t)b * SPA * CCH;

    const int srow = t >> 3;
    const int scol = (t & 7) ^ (srow & 7);
    const char* gA = (const char*)(A  + (size_t)(o0 + srow) * CCH) + scol * 16;
    const char* gB = (const char*)(Bb + (size_t)(s0 + srow) * CCH) + scol * 16;
    char* lA = (char*)sA + w * 1024;
    char* lB = (char*)sB + w * 1024;

    const int wm = w >> 1, wn = w & 1;
    const int lr = lane & 15, kh = lane >> 4;
    const int ar0 = wm * 32 + lr, ar1 = ar0 + 16;
    const int br0 = wn * 32 + lr, br1 = br0 + 16;

    f32x4 acc[2][2] = {};
    for (int kt = 0; kt < 4; ++kt) {
        __builtin_amdgcn_global_load_lds(
            (const __attribute__((address_space(1))) void*)(gA + kt * 128),
            (__attribute__((address_space(3))) void*)lA, 16, 0, 0);
        __builtin_amdgcn_global_load_lds(
            (const __attribute__((address_space(1))) void*)(gA + 16384 + kt * 128),
            (__attribute__((address_space(3))) void*)(lA + 4096), 16, 0, 0);
        __builtin_amdgcn_global_load_lds(
            (const __attribute__((address_space(1))) void*)(gB + kt * 128),
            (__attribute__((address_space(3))) void*)lB, 16, 0, 0);
        __builtin_amdgcn_global_load_lds(
            (const __attribute__((address_space(1))) void*)(gB + 16384 + kt * 128),
            (__attribute__((address_space(3))) void*)(lB + 4096), 16, 0, 0);
        __syncthreads();
#pragma unroll
        for (int kk = 0; kk < 2; ++kk) {
            const int kg = (kk << 2) | kh;
            short8 a0 = *(const short8*)&sA[(ar0 * 128 + ((kg ^ (ar0 & 7)) << 4)) >> 1];
            short8 a1 = *(const short8*)&sA[(ar1 * 128 + ((kg ^ (ar1 & 7)) << 4)) >> 1];
            short8 b0 = *(const short8*)&sB[(br0 * 128 + ((kg ^ (br0 & 7)) << 4)) >> 1];
            short8 b1 = *(const short8*)&sB[(br1 * 128 + ((kg ^ (br1 & 7)) << 4)) >> 1];
            acc[0][0] = __builtin_amdgcn_mfma_f32_16x16x32_bf16(a0, b0, acc[0][0], 0, 0, 0);
            acc[0][1] = __builtin_amdgcn_mfma_f32_16x16x32_bf16(a0, b1, acc[0][1], 0, 0, 0);
            acc[1][0] = __builtin_amdgcn_mfma_f32_16x16x32_bf16(a1, b0, acc[1][0], 0, 0, 0);
            acc[1][1] = __builtin_amdgcn_mfma_f32_16x16x32_bf16(a1, b1, acc[1][1], 0, 0, 0);
        }
        __syncthreads();
    }
#pragma unroll
    for (int mi = 0; mi < 2; ++mi)
#pragma unroll
        for (int ni = 0; ni < 2; ++ni) {
            const int r0 = o0 + wm * 32 + mi * 16 + kh * 4;
            const int cc = s0 + wn * 32 + ni * 16 + lr;
            if constexpr (OBF) {
                __hip_bfloat16* Cb = (__hip_bfloat16*)Cv + (size_t)b * M * SPA;
#pragma unroll
                for (int q = 0; q < 4; ++q)
                    Cb[(size_t)(r0 + q) * SPA + cc] = __float2bfloat16(acc[mi][ni][q]);
            } else {
                float* Cb = (float*)Cv + (size_t)b * M * SPA;
#pragma unroll
                for (int q = 0; q < 4; ++q)
                    Cb[(size_t)(r0 + q) * SPA + cc] = acc[mi][ni][q];
            }
        }
}

// ---------------- K2: depthwise 3x3 SAME, x4 along w, bf16 in/out (r11 verbatim)
__global__ __launch_bounds__(256) void k_dw(const __hip_bfloat16* __restrict__ y1,
                                            const float* __restrict__ w2,
                                            __hip_bfloat16* __restrict__ y2) {
    int idx = blockIdx.x * 256 + threadIdx.x;   // 1204224 exact
    int tw = idx % 14;
    int rest = idx / 14;
    int h = rest % HGT;
    int bc = rest / HGT;
    int w0 = tw * 4;
    const __hip_bfloat16* in = y1 + (size_t)bc * SPA;
    const float* wt = w2 + (bc % C3) * 9;
    float a0 = 0.f, a1 = 0.f, a2 = 0.f, a3 = 0.f;
#pragma unroll
    for (int dh = -1; dh <= 1; ++dh) {
        int hh = h + dh;
        if (hh < 0 || hh >= HGT) continue;
        const __hip_bfloat16* rp = in + hh * WID + w0;
        ushort4 c4 = *(const ushort4*)rp;
        float c0 = bfu(c4.x), c1 = bfu(c4.y), c2 = bfu(c4.z), c3 = bfu(c4.w);
        float l = (w0 > 0)  ? bfu(*(const unsigned short*)(rp - 1)) : 0.f;
        float r = (w0 < 52) ? bfu(*(const unsigned short*)(rp + 4)) : 0.f;
        float wl = wt[(dh + 1) * 3 + 0];
        float wc = wt[(dh + 1) * 3 + 1];
        float wr = wt[(dh + 1) * 3 + 2];
        a0 += wl * l  + wc * c0 + wr * c1;
        a1 += wl * c0 + wc * c1 + wr * c2;
        a2 += wl * c1 + wc * c2 + wr * c3;
        a3 += wl * c2 + wc * c3 + wr * r;
    }
    ushort4 o;
    o.x = f2bf_bits(a0); o.y = f2bf_bits(a1);
    o.z = f2bf_bits(a2); o.w = f2bf_bits(a3);
    *(ushort4*)(y2 + (size_t)bc * SPA + h * WID + w0) = o;
}

// ---------------- K3 v7f: MFMA attention (r16 body; per-u __syncthreads ->
// zero-cost compiler fence. sP is strictly per-wave and same-wave DS ops are
// in-order in HW (v3-v6 precedent); the fence only blocks TBAA hoisting of the
// short8 read above the uint2 write (the r9 NaN mechanism).
template<int D>
__device__ __forceinline__ void attn7_body(short* __restrict__ sK,
                                           short* __restrict__ sVT,
                                           short* __restrict__ sQ,
                                           short* __restrict__ sP,
                                           float* __restrict__ sEB,
                                           const __hip_bfloat16* __restrict__ y2,
                                           const float* __restrict__ rpb,
                                           __hip_bfloat16* __restrict__ opre,
                                           int b, int head, int i, int hsub) {
    const int tid = threadIdx.x;
    const int lane = tid & 63, w = tid >> 6;
    const int lr = lane & 15, kh = lane >> 4;

    int wsi, pbi;
    if (D == 1) {
        wsi = (i < 3) ? 0 : ((i > 52) ? 49 : i - 3);
        pbi = (i < 3) ? 6 - i : ((i > 52) ? 55 - i : 3);
    } else {
        wsi = (i < 6) ? (i & 1) : ((i >= 50) ? 42 + (i & 1) : i - 6);
        pbi = (i < 6) ? 6 - (i >> 1) : ((i >= 50) ? (55 - i) >> 1 : 3);
    }

    const __hip_bfloat16* base  = y2 + (size_t)b * YB + head * HD;
    const __hip_bfloat16* kbase = base + CCH     + wsi * ISTR;
    const __hip_bfloat16* vbase = base + 2 * CCH + wsi * ISTR;
    const __hip_bfloat16* qbase = base + i * ISTR;

    // ---- K stage: [u 7][kj 64][d 32], rows 64B, XOR key kj&3; kj>=56 clamped
    for (int f = tid; f < 1792; f += 256) {
        int u = f >> 8, rem = f & 255, kj = rem >> 2, slot = rem & 3;
        int kjc = (kj > 55) ? 55 : kj;
        const __hip_bfloat16* src = kbase + u * (D * ISTR) + kjc * JSTR + ((slot ^ (kj & 3)) << 3);
        char* dst = (char*)sK + (size_t)(f - lane) * 16;
        __builtin_amdgcn_global_load_lds(
            (const __attribute__((address_space(1))) void*)src,
            (__attribute__((address_space(3))) void*)dst, 16, 0, 0);
    }
    // ---- Q stage: [j 64][d 32]; rows >=56 clamped (unused)
    {
        int jq = tid >> 2, slot = tid & 3;
        int jqc = (jq > 55) ? 55 : jq;
        const __hip_bfloat16* src = qbase + jqc * JSTR + ((slot ^ (jq & 3)) << 3);
        char* dst = (char*)sQ + (size_t)(tid - lane) * 16;
        __builtin_amdgcn_global_load_lds(
            (const __attribute__((address_space(1))) void*)src,
            (__attribute__((address_space(3))) void*)dst, 16, 0, 0);
    }
    // ---- V^T stage (16B-wide): [u 7][d 32][kj 64], rows 128B, XOR key d&7.
    for (int f = tid; f < 784; f += 256) {
        int u = f / 112, rem = f - u * 112;
        int dq8 = rem / 28, kjp = rem - dq8 * 28;
        const __hip_bfloat16* g0 = vbase + u * (D * ISTR) + (2 * kjp) * JSTR + dq8 * 8;
        short8 va8 = *(const short8*)g0;
        short8 vb8 = *(const short8*)(g0 + JSTR);
        const int kjhi = kjp >> 2;
        char* bvt = (char*)sVT + (u * 32 + dq8 * 8) * 128 + (kjp & 3) * 4;
#pragma unroll
        for (int e = 0; e < 8; ++e) {
            unsigned pk = (unsigned)(unsigned short)va8[e] |
                          ((unsigned)(unsigned short)vb8[e] << 16);
            *(unsigned*)(bvt + e * 128 + ((kjhi ^ e) << 4)) = pk;
        }
    }
    if (tid < 224) {   // V^T pad (kj 56..63) = 0
        int u = tid >> 5, d = tid & 31;
        int row = u * 32 + d;
        int byt = row * 128 + ((7 ^ (d & 7)) << 4);
        *(short8*)((char*)sVT + byt) = (short8){0, 0, 0, 0, 0, 0, 0, 0};
    }
    if (tid < 91) {
        int u = tid / 13, r = tid - u * 13;
        sEB[tid] = __expf(rpb[hsub * 169 + (pbi + u) * 13 + r]);
    }
    __syncthreads();

    const int j = w * 16 + lr;
    int wsj;
    if (D == 1) wsj = (j < 3) ? 0 : ((j > 52) ? 49 : j - 3);
    else        wsj = (j < 6) ? (j & 1) : ((j >= 50) ? 42 + (j & 1) : j - 6);

    short8 qf = *(const short8*)((char*)sQ + j * 64 + ((kh ^ (j & 3)) << 4));

    // ---- hoisted u-invariant mask + bias-row index
    int rr[16];
    unsigned vmask = 0;
#pragma unroll
    for (int Mt = 0; Mt < 4; ++Mt)
#pragma unroll
        for (int q = 0; q < 4; ++q) {
            const int idx = Mt * 4 + q;
            const int kj = Mt * 16 + (kh << 2) + q;
            const int rel = kj - j;
            const int din = kj - wsj;
            bool valid = (din >= 0) && (din <= 6 * D);
            if (D == 2) valid = valid && ((rel & 1) == 0);
            const int r = (D == 1) ? (rel + 6) : ((rel >> 1) + 6);
            rr[idx] = valid ? r : 0;           // valid r is in [0,12]; 0 is safe
            vmask |= (valid ? 1u : 0u) << idx;
        }

    float ssum = 0.f;
    f32x4 oacc0 = {0.f, 0.f, 0.f, 0.f};
    f32x4 oacc1 = {0.f, 0.f, 0.f, 0.f};
    short* sPw = sP + w * 2048;

#pragma unroll
    for (int u = 0; u < 7; ++u) {
        char* sPb = (char*)(sPw + (u & 1) * 1024);
        f32x4 s[4];
#pragma unroll
        for (int Mt = 0; Mt < 4; ++Mt) {
            int kjrow = u * 64 + Mt * 16 + lr;
            short8 kf = *(const short8*)((char*)sK + kjrow * 64 + ((kh ^ (lr & 3)) << 4));
            s[Mt] = __builtin_amdgcn_mfma_f32_16x16x32_bf16(kf, qf,
                        (f32x4){0.f, 0.f, 0.f, 0.f}, 0, 0, 0);
        }
        const float* ebu = sEB + u * 13;
#pragma unroll
        for (int Mt = 0; Mt < 4; ++Mt) {
            float ev[4];
#pragma unroll
            for (int q = 0; q < 4; ++q) {
                const int idx = Mt * 4 + q;
                float ex = __expf(s[Mt][q] * SCALE_Q) * ebu[rr[idx]];
                ev[q] = ((vmask >> idx) & 1u) ? ex : 0.f;
                ssum += ev[q];
            }
            uint2 pk2;
            pk2.x = pk2bf(ev[0], ev[1]);
            pk2.y = pk2bf(ev[2], ev[3]);
            int g = Mt * 2 + (kh >> 1);
            int byt = lr * 128 + (((g ^ (lr & 7)) << 4)) + (kh & 1) * 8;
            *(uint2*)(sPb + byt) = pk2;
        }
        // ---- compiler-only fence: forbid hoisting the short8 pf read above
        // the uint2 P writes (TBAA no-alias). HW same-wave DS ops are in-order,
        // and sPb is private to this wave -> no block barrier needed.
        asm volatile("" ::: "memory");
#pragma unroll
        for (int Kt = 0; Kt < 2; ++Kt) {
            short8 pf = *(const short8*)(sPb + lr * 128 + ((((Kt * 4 + kh) ^ (lr & 7)) << 4)));
            {
                int row = u * 32 + lr;
                short8 vf = *(const short8*)((char*)sVT + row * 128 +
                              ((((Kt * 4 + kh) ^ (lr & 7)) << 4)));
                oacc0 = __builtin_amdgcn_mfma_f32_16x16x32_bf16(vf, pf, oacc0, 0, 0, 0);
            }
            {
                int row = u * 32 + 16 + lr;
                short8 vf = *(const short8*)((char*)sVT + row * 128 +
                              ((((Kt * 4 + kh) ^ (lr & 7)) << 4)));
                oacc1 = __builtin_amdgcn_mfma_f32_16x16x32_bf16(vf, pf, oacc1, 0, 0, 0);
            }
        }
    }

    // full softmax denominator: combine the 4 kh-group partials (same j = lr)
    ssum += __shfl_xor(ssum, 16);
    ssum += __shfl_xor(ssum, 32);

    if (j < 56) {
        const float rinv = __frcp_rn(ssum);
        const size_t ob = (size_t)b * (SPA * CCH) + (size_t)(i * WID + j) * CCH
                          + head * HD + (kh << 2);
        uint2 p0, p1;
        p0.x = pk2bf(oacc0[0] * rinv, oacc0[1] * rinv);
        p0.y = pk2bf(oacc0[2] * rinv, oacc0[3] * rinv);
        p1.x = pk2bf(oacc1[0] * rinv, oacc1[1] * rinv);
        p1.y = pk2bf(oacc1[2] * rinv, oacc1[3] * rinv);
        *(uint2*)&opre[ob]      = p0;
        *(uint2*)&opre[ob + 16] = p1;
    }
}

__global__ __launch_bounds__(256) void k_attn7(const __hip_bfloat16* __restrict__ y2,
                                               const float* __restrict__ rpb0,
                                               const float* __restrict__ rpb1,
                                               __hip_bfloat16* __restrict__ opre) {
    __shared__ __align__(16) short sK[14336];    // 28KB
    __shared__ __align__(16) short sVT[14336];   // 28KB
    __shared__ __align__(16) short sQ[2048];     // 4KB
    __shared__ __align__(16) short sP[8192];     // 16KB (4 waves x 2 bufs)
    __shared__ float sEB[91];
    const int i = blockIdx.x;
    const int bh = blockIdx.y;
    const int b = bh >> 3, head = bh & 7;
    if (head < 4)
        attn7_body<1>(sK, sVT, sQ, sP, sEB, y2, rpb0, opre, b, head, i, head);
    else
        attn7_body<2>(sK, sVT, sQ, sP, sEB, y2, rpb1, opre, b, head, i, head - 4);
}

extern "C" void kernel_launch(void* const* d_in, const int* in_sizes, int n_in,
                              void* d_out, int out_size, void* d_ws, size_t ws_size,
                              hipStream_t stream) {
    const float* x    = (const float*)d_in[0];
    const float* w1   = (const float*)d_in[1];
    const float* w2   = (const float*)d_in[2];
    const float* rpb0 = (const float*)d_in[3];
    const float* rpb1 = (const float*)d_in[4];
    const float* wp   = (const float*)d_in[5];
    float* out = (float*)d_out;

    float* p = (float*)d_ws;
    __hip_bfloat16* y1b  = (__hip_bfloat16*)p;             // [2][768][3136] bf16
    __hip_bfloat16* y2b  = (__hip_bfloat16*)(p + YB);      // [2][768][3136] bf16
    __hip_bfloat16* xT   = (__hip_bfloat16*)(p + 2 * YB);  // [2][3136][256] bf16
    __hip_bfloat16* opre = xT;                             // disjoint lifetimes
    __hip_bfloat16* w1b  = (__hip_bfloat16*)(p + 2 * YB + 802816);
    __hip_bfloat16* wpb  = (__hip_bfloat16*)(p + 2 * YB + 802816 + 98304);

    k_cvt<<<dim3(49, 4, 3), 256, 0, stream>>>(x, w1, wp, xT, w1b, wpb);
    k_qkv2<<<dim3(49, 6, 2), 256, 0, stream>>>(w1b, xT, y1b);
    k_dw<<<dim3(4704), 256, 0, stream>>>(y1b, w2, y2b);
    k_attn7<<<dim3(HGT, 2 * NH), 256, 0, stream>>>(y2b, rpb0, rpb1, opre);
    k_gemm<false><<<dim3(49, 4, 2), 256, 0, stream>>>(wpb, opre, out, CCH);
}